// Round 13
// baseline (1705.128 us; speedup 1.0000x reference)
//
#include <hip/hip_runtime.h>

#define NPTS 4096
#define NPT  1024
#define BATCH 16
#define GRID_BLOCKS 512
#define SMEM_BYTES 54272   // max(FPS 53248, act 53248 + slist 1024)

typedef __attribute__((ext_vector_type(8))) short bf16x8;
typedef __attribute__((ext_vector_type(4))) float f32x4;

__device__ __forceinline__ unsigned short f2bf(float f) {
    unsigned u = __float_as_uint(f);
    u += 0x7fffu + ((u >> 16) & 1u);      // RNE; finite inputs only
    return (unsigned short)(u >> 16);
}

// ---------------------------------------------------------------------------
// DPP helper: packed u64 keymax carrying coords (FPS reduction).
// key = (float_bits(dist)<<32)|~idx; dist>=0 -> monotone bits; ~idx ties
// toward the smaller index (== jnp.argmax first-max).
// ---------------------------------------------------------------------------
template <int CTRL>
__device__ __forceinline__ void dpp_keymax_xyz(unsigned long long& key,
                                               float& x, float& y, float& z)
{
    const int klo = (int)(unsigned int)key;
    const int khi = (int)(unsigned int)(key >> 32);
    const int nlo = __builtin_amdgcn_update_dpp(0, klo, CTRL, 0xF, 0xF, false);
    const int nhi = __builtin_amdgcn_update_dpp(0, khi, CTRL, 0xF, 0xF, false);
    const int nx  = __builtin_amdgcn_update_dpp(0, __float_as_int(x), CTRL, 0xF, 0xF, false);
    const int ny  = __builtin_amdgcn_update_dpp(0, __float_as_int(y), CTRL, 0xF, 0xF, false);
    const int nz  = __builtin_amdgcn_update_dpp(0, __float_as_int(z), CTRL, 0xF, 0xF, false);
    const unsigned long long ok =
        ((unsigned long long)(unsigned int)nhi << 32) | (unsigned int)nlo;
    const bool gt = ok > key;
    key = gt ? ok : key;
    x = gt ? __int_as_float(nx) : x;
    y = gt ? __int_as_float(ny) : y;
    z = gt ? __int_as_float(nz) : z;
}

// Bounded acquire-spin on the producer's progress counter.
__device__ __forceinline__ void wait_progress(int* progress, int b, int need)
{
    int guard = 0;
    while (__hip_atomic_load(&progress[b], __ATOMIC_ACQUIRE,
                             __HIP_MEMORY_SCOPE_AGENT) < need) {
        if (++guard > (1 << 22)) break;   // safety valve: fail loud, not hung
        __builtin_amdgcn_s_sleep(16);
    }
}

// ---------------------------------------------------------------------------
// FPS role (blocks 0..15): identical selection math to rounds 10-12
// (bit-exact). NEW: chunked flush of new_xyz/idx to global every 128 steps +
// device-scope release publish of progress[b]; final flush + publish 1024.
// ---------------------------------------------------------------------------
__device__ void fps_role(const float* __restrict__ xyz,
                         float* __restrict__ out_nxyz,
                         float* __restrict__ out_idxf,
                         int* __restrict__ progress,
                         char* smem, float4 (*pr0)[4], float (*pr1)[4])
{
    float* sx  = (float*)smem;
    float* sy  = sx + NPTS;
    float* sz  = sy + NPTS;
    int*  sidx = (int*)(smem + 3 * NPTS * sizeof(float));

    const int tid  = threadIdx.x;
    const int b    = blockIdx.x;
    const int lane = tid & 63;
    const int wid  = tid >> 6;

    __builtin_amdgcn_s_setprio(1);   // protect the serial chain from SA waves

    const float* bx = xyz + (size_t)b * NPTS * 3;
    for (int p = tid; p < NPTS; p += 256) {
        sx[p] = bx[3 * p];
        sy[p] = bx[3 * p + 1];
        sz[p] = bx[3 * p + 2];
    }
    if (tid == 0) sidx[0] = 0;
    __syncthreads();

    float rx[16], ry[16], rz[16], dist[16];
#pragma unroll
    for (int j = 0; j < 16; ++j) {
        const int p = tid + j * 256;
        rx[j] = sx[p]; ry[j] = sy[p]; rz[j] = sz[p];
        dist[j] = 1e10f;
    }
    float lx = sx[0], ly = sy[0], lz = sz[0];

    for (int step = 1; step < NPT; ++step) {
        float bv = -1.0f;
        int   bp = 0;
        float bxl = 0.0f, byl = 0.0f, bzl = 0.0f;
#pragma unroll
        for (int j = 0; j < 16; ++j) {
            const int p = tid + j * 256;
            const float dx = __fsub_rn(rx[j], lx);
            const float dy = __fsub_rn(ry[j], ly);
            const float dz = __fsub_rn(rz[j], lz);
            const float d  = __fadd_rn(__fadd_rn(__fmul_rn(dx, dx), __fmul_rn(dy, dy)),
                                       __fmul_rn(dz, dz));
            const float nd = fminf(dist[j], d);
            dist[j] = nd;
            const bool gt = nd > bv;
            bv  = gt ? nd    : bv;
            bp  = gt ? p     : bp;
            bxl = gt ? rx[j] : bxl;
            byl = gt ? ry[j] : byl;
            bzl = gt ? rz[j] : bzl;
        }
        unsigned long long key =
            ((unsigned long long)__float_as_uint(bv) << 32) |
            (unsigned int)(~bp);

        dpp_keymax_xyz<0x111>(key, bxl, byl, bzl);   // row_shr:1
        dpp_keymax_xyz<0x112>(key, bxl, byl, bzl);   // row_shr:2
        dpp_keymax_xyz<0x114>(key, bxl, byl, bzl);   // row_shr:4
        dpp_keymax_xyz<0x118>(key, bxl, byl, bzl);   // row_shr:8
        dpp_keymax_xyz<0x142>(key, bxl, byl, bzl);   // row_bcast15
        dpp_keymax_xyz<0x143>(key, bxl, byl, bzl);   // row_bcast31 -> lane63

        const int par = step & 1;
        if (lane == 63) {
            pr0[par][wid] = make_float4(
                __int_as_float((int)(unsigned int)key),
                __int_as_float((int)(unsigned int)(key >> 32)),
                bxl, byl);
            pr1[par][wid] = bzl;
        }
        __syncthreads();

        // chunked flush of [step-128, step) by wave 0, then release-publish
        if ((step & 127) == 0) {
            if (wid == 0) {
#pragma unroll 1
                for (int e = step - 128 + lane; e < step; e += 64) {
                    const int ix = sidx[e];
                    out_idxf[b * NPT + e] = (float)ix;
                    out_nxyz[(size_t)(b * NPT + e) * 3 + 0] = sx[ix];
                    out_nxyz[(size_t)(b * NPT + e) * 3 + 1] = sy[ix];
                    out_nxyz[(size_t)(b * NPT + e) * 3 + 2] = sz[ix];
                }
                __threadfence();
                if (lane == 0)
                    __hip_atomic_store(&progress[b], step, __ATOMIC_RELEASE,
                                       __HIP_MEMORY_SCOPE_AGENT);
            }
        }

        const float4 r   = pr0[par][lane & 3];
        const float  rzz = pr1[par][lane & 3];
        unsigned long long gkey =
            ((unsigned long long)(unsigned int)__float_as_int(r.y) << 32) |
            (unsigned int)__float_as_int(r.x);
        float gx = r.z, gy = r.w, gz = rzz;
        dpp_keymax_xyz<0xB1>(gkey, gx, gy, gz);   // quad_perm xor1
        dpp_keymax_xyz<0x4E>(gkey, gx, gy, gz);   // quad_perm xor2

        lx = gx; ly = gy; lz = gz;
        if (tid == 0) sidx[step] = (int)(~(unsigned int)gkey);
    }
    __syncthreads();

    // final flush [896, 1024)
    for (int e = 896 + tid; e < NPT; e += 256) {
        const int ix = sidx[e];
        out_idxf[b * NPT + e] = (float)ix;
        out_nxyz[(size_t)(b * NPT + e) * 3 + 0] = sx[ix];
        out_nxyz[(size_t)(b * NPT + e) * 3 + 1] = sy[ix];
        out_nxyz[(size_t)(b * NPT + e) * 3 + 2] = sz[ix];
    }
    __threadfence();
    __syncthreads();
    if (tid == 0)
        __hip_atomic_store(&progress[b], NPT, __ATOMIC_RELEASE,
                           __HIP_MEMORY_SCOPE_AGENT);
    __builtin_amdgcn_s_setprio(0);
    __syncthreads();   // smem reused by SA items below
}

// ---------------------------------------------------------------------------
// MFMA SA role (K in {32,64}) -- r12's verified body; blockIdx -> item, and
// per-wave acquire-spin on this wave's query span. All LDS per-wid partitioned
// (act quarter + slist 64-entry slice) -> zero barriers, waves drift freely.
// ---------------------------------------------------------------------------
template <int K, int F0, int F1, int F2, int CH_OFF>
__device__ void sa_mfma_role(int item,
                             const float* __restrict__ xyz,
                             const float* __restrict__ points,
                             const float* __restrict__ newxyz,
                             const float* __restrict__ w0,
                             const float* __restrict__ w1,
                             const float* __restrict__ w2,
                             float* __restrict__ out1,
                             float r2, int* __restrict__ progress, char* smem)
{
    constexpr int TPQ = K / 16;
    constexpr int QW  = 4 / TPQ;
    constexpr int KF1 = F0 / 32;
    constexpr int KF2 = F1 / 32;
    constexpr int NT0 = F0 / 16, NT1 = F1 / 16, NT2 = F2 / 16;
    constexpr int NH1 = NT1 / 2;
    constexpr int STRIDE = 104;
    constexpr unsigned long long KMASK =
        (K == 64) ? ~0ULL : ((1ULL << K) - 1ULL);

    const int tid  = threadIdx.x;
    const int lane = tid & 63;
    const int wid  = tid >> 6;
    unsigned short* __restrict__ A = (unsigned short*)smem + wid * 64 * STRIDE;
    int* __restrict__ slist = (int*)(smem + 4 * 64 * STRIDE * 2);

    const int k    = lane & (K - 1);
    const int qsub = lane / K;
    const int qid  = (item * 4 + wid) * QW + qsub;
    const int b    = qid >> 10;

    // wait until this wave's queries are published
    wait_progress(progress, b, (((item * 4 + wid) * QW) & 1023) + QW);

    const float qx = newxyz[(size_t)qid * 3 + 0];
    const float qy = newxyz[(size_t)qid * 3 + 1];
    const float qz = newxyz[(size_t)qid * 3 + 2];
    const float* bxyz = xyz + (size_t)b * NPTS * 3;

    // ---- ball query (bit-exact fp32, first-K ascending) ----
    int cnt = 0;
    const int gbase = wid * 64 + qsub * K;
    for (int c0 = 0; c0 < NPTS; c0 += K) {
        bool hit = false;
        const int p = c0 + k;
        if (cnt < K) {
            const float dx = __fsub_rn(qx, bxyz[3 * p]);
            const float dy = __fsub_rn(qy, bxyz[3 * p + 1]);
            const float dz = __fsub_rn(qz, bxyz[3 * p + 2]);
            const float d2 = __fadd_rn(__fadd_rn(__fmul_rn(dx, dx), __fmul_rn(dy, dy)),
                                       __fmul_rn(dz, dz));
            hit = d2 < r2;
        }
        const unsigned long long bal = __ballot(hit);
        const unsigned long long gm  = (bal >> (qsub * K)) & KMASK;
        const int pre = __popcll(gm & ((1ULL << k) - 1ULL));
        const int pos = cnt + pre;
        if (hit && pos < K) slist[gbase + pos] = p;
        cnt = min(cnt + (int)__popcll(gm), K);
        if (__all(cnt >= K)) break;
    }
    const int nbr = slist[gbase + ((k < cnt) ? k : 0)];

    // ---- gather -> LDS bf16 row ----
    {
        unsigned short e[32];
        const float4* prow = (const float4*)(points + ((size_t)b * NPTS + nbr) * 16);
        const float4 p0 = prow[0], p1 = prow[1], p2 = prow[2], p3 = prow[3];
        e[0]  = f2bf(p0.x); e[1]  = f2bf(p0.y); e[2]  = f2bf(p0.z); e[3]  = f2bf(p0.w);
        e[4]  = f2bf(p1.x); e[5]  = f2bf(p1.y); e[6]  = f2bf(p1.z); e[7]  = f2bf(p1.w);
        e[8]  = f2bf(p2.x); e[9]  = f2bf(p2.y); e[10] = f2bf(p2.z); e[11] = f2bf(p2.w);
        e[12] = f2bf(p3.x); e[13] = f2bf(p3.y); e[14] = f2bf(p3.z); e[15] = f2bf(p3.w);
        e[16] = f2bf(__fsub_rn(bxyz[3 * nbr],     qx));
        e[17] = f2bf(__fsub_rn(bxyz[3 * nbr + 1], qy));
        e[18] = f2bf(__fsub_rn(bxyz[3 * nbr + 2], qz));
#pragma unroll
        for (int j = 19; j < 32; ++j) e[j] = 0;
        unsigned int* dst = (unsigned int*)&A[lane * STRIDE];
#pragma unroll
        for (int j = 0; j < 16; ++j)
            dst[j] = ((unsigned int)e[2 * j + 1] << 16) | e[2 * j];
    }

    const int lr = lane & 15;
    const int lg = lane >> 4;

    // ---- layer 1 ----
    bf16x8 a1[4];
#pragma unroll
    for (int m = 0; m < 4; ++m)
        a1[m] = *(const bf16x8*)&A[(m * 16 + lr) * STRIDE + lg * 8];

    bf16x8 b1[NT0];
#pragma unroll
    for (int n = 0; n < NT0; ++n) {
#pragma unroll
        for (int j = 0; j < 8; ++j) {
            const int kk = lg * 8 + j;
            const int kc = (kk < 19) ? kk : 18;
            const float v = w0[kc * F0 + n * 16 + lr];
            b1[n][j] = (kk < 19) ? (short)f2bf(v) : (short)0;
        }
    }
    f32x4 c1[4][NT0];
#pragma unroll
    for (int m = 0; m < 4; ++m)
#pragma unroll
        for (int n = 0; n < NT0; ++n) {
            f32x4 z = {0.0f, 0.0f, 0.0f, 0.0f};
            c1[m][n] = __builtin_amdgcn_mfma_f32_16x16x32_bf16(a1[m], b1[n], z, 0, 0, 0);
        }
#pragma unroll
    for (int m = 0; m < 4; ++m)
#pragma unroll
        for (int n = 0; n < NT0; ++n)
#pragma unroll
            for (int r = 0; r < 4; ++r)
                A[(m * 16 + lg * 4 + r) * STRIDE + n * 16 + lr] =
                    f2bf(fmaxf(c1[m][n][r], 0.0f));

    // ---- layer 2 (two n-halves) ----
    bf16x8 a2[4][KF1];
#pragma unroll
    for (int m = 0; m < 4; ++m)
#pragma unroll
        for (int kf = 0; kf < KF1; ++kf)
            a2[m][kf] = *(const bf16x8*)&A[(m * 16 + lr) * STRIDE + kf * 32 + lg * 8];

#pragma unroll
    for (int half = 0; half < 2; ++half) {
        bf16x8 b2[NH1][KF1];
#pragma unroll
        for (int n = 0; n < NH1; ++n)
#pragma unroll
            for (int kf = 0; kf < KF1; ++kf)
#pragma unroll
                for (int j = 0; j < 8; ++j) {
                    const int kk = kf * 32 + lg * 8 + j;
                    b2[n][kf][j] = (short)f2bf(w1[(size_t)kk * F1 + (half * NH1 + n) * 16 + lr]);
                }
        f32x4 c2[4][NH1];
#pragma unroll
        for (int m = 0; m < 4; ++m)
#pragma unroll
            for (int n = 0; n < NH1; ++n) {
                f32x4 z = {0.0f, 0.0f, 0.0f, 0.0f};
#pragma unroll
                for (int kf = 0; kf < KF1; ++kf)
                    z = __builtin_amdgcn_mfma_f32_16x16x32_bf16(a2[m][kf], b2[n][kf], z, 0, 0, 0);
                c2[m][n] = z;
            }
#pragma unroll
        for (int m = 0; m < 4; ++m)
#pragma unroll
            for (int n = 0; n < NH1; ++n)
#pragma unroll
                for (int r = 0; r < 4; ++r)
                    A[(m * 16 + lg * 4 + r) * STRIDE + (half * NH1 + n) * 16 + lr] =
                        f2bf(fmaxf(c2[m][n][r], 0.0f));
    }

    // ---- layer 3 + relu + pool + store ----
    bf16x8 a3[4][KF2];
#pragma unroll
    for (int m = 0; m < 4; ++m)
#pragma unroll
        for (int kf = 0; kf < KF2; ++kf)
            a3[m][kf] = *(const bf16x8*)&A[(m * 16 + lr) * STRIDE + kf * 32 + lg * 8];

    const int qbase = (item * 4 + wid) * QW;
#pragma unroll
    for (int n = 0; n < NT2; ++n) {
        bf16x8 b3[KF2];
#pragma unroll
        for (int kf = 0; kf < KF2; ++kf)
#pragma unroll
            for (int j = 0; j < 8; ++j) {
                const int kk = kf * 32 + lg * 8 + j;
                b3[kf][j] = (short)f2bf(w2[(size_t)kk * F2 + n * 16 + lr]);
            }
        float q0 = 0.0f, q1 = 0.0f;
#pragma unroll
        for (int m = 0; m < 4; ++m) {
            f32x4 c = {0.0f, 0.0f, 0.0f, 0.0f};
#pragma unroll
            for (int kf = 0; kf < KF2; ++kf)
                c = __builtin_amdgcn_mfma_f32_16x16x32_bf16(a3[m][kf], b3[kf], c, 0, 0, 0);
            float v = fmaxf(fmaxf(c[0], c[1]), fmaxf(c[2], c[3]));
            v = fmaxf(v, 0.0f);
            v = fmaxf(v, __shfl_xor(v, 16));
            v = fmaxf(v, __shfl_xor(v, 32));
            if (QW == 1) {
                q0 = fmaxf(q0, v);
            } else {
                if (m < 2) q0 = fmaxf(q0, v); else q1 = fmaxf(q1, v);
            }
        }
        if (lg < QW) {
            const float val = (QW == 2 && lg == 1) ? q1 : q0;
            out1[(size_t)(qbase + lg) * 320 + CH_OFF + n * 16 + lr] = val;
        }
    }
}

// ---------------------------------------------------------------------------
// fp32 SA role for scale 0 (K=16, 16 q/item) -- r7/r12 fused-stream body.
// slist lives in the per-wid slice at smem+53248 (disjoint from act).
// ---------------------------------------------------------------------------
template <int K, int F0, int F1, int F2, int CH_OFF>
__device__ void sa_fp32_role(int item,
                             const float* __restrict__ xyz,
                             const float* __restrict__ points,
                             const float* __restrict__ newxyz,
                             const float* __restrict__ w0,
                             const float* __restrict__ w1,
                             const float* __restrict__ w2,
                             float* __restrict__ out1,
                             float r2, int* __restrict__ progress, char* smem)
{
    constexpr int QPW = 64 / K;   // 4
    constexpr unsigned long long KMASK = (1ULL << K) - 1ULL;

    int* __restrict__ slist = (int*)(smem + 4 * 64 * 104 * 2);

    const int tid  = threadIdx.x;
    const int lane = tid & 63;
    const int wid  = tid >> 6;
    const int k    = lane & (K - 1);
    const int qsub = lane / K;
    const int qid  = (item * 4 + wid) * QPW + qsub;
    const int b    = qid >> 10;

    wait_progress(progress, b, (((item * 4 + wid) * QPW) & 1023) + QPW);

    const float qx = newxyz[(size_t)qid * 3 + 0];
    const float qy = newxyz[(size_t)qid * 3 + 1];
    const float qz = newxyz[(size_t)qid * 3 + 2];
    const float* bxyz = xyz + (size_t)b * NPTS * 3;

    int cnt = 0;
    const int gbase = wid * 64 + qsub * K;
    for (int c0 = 0; c0 < NPTS; c0 += K) {
        bool hit = false;
        const int p = c0 + k;
        if (cnt < K) {
            const float dx = __fsub_rn(qx, bxyz[3 * p]);
            const float dy = __fsub_rn(qy, bxyz[3 * p + 1]);
            const float dz = __fsub_rn(qz, bxyz[3 * p + 2]);
            const float d2 = __fadd_rn(__fadd_rn(__fmul_rn(dx, dx), __fmul_rn(dy, dy)),
                                       __fmul_rn(dz, dz));
            hit = d2 < r2;
        }
        const unsigned long long bal = __ballot(hit);
        const unsigned long long gm  = (bal >> (qsub * K)) & KMASK;
        const int pre = __popcll(gm & ((1ULL << k) - 1ULL));
        const int pos = cnt + pre;
        if (hit && pos < K) slist[gbase + pos] = p;
        cnt = min(cnt + (int)__popcll(gm), K);
        if (__all(cnt >= K)) break;
    }
    const int nbr = slist[gbase + ((k < cnt) ? k : 0)];

    float a0r[19];
    {
        const float4* prow = (const float4*)(points + ((size_t)b * NPTS + nbr) * 16);
        const float4 p0 = prow[0], p1 = prow[1], p2 = prow[2], p3 = prow[3];
        a0r[0]  = p0.x; a0r[1]  = p0.y; a0r[2]  = p0.z; a0r[3]  = p0.w;
        a0r[4]  = p1.x; a0r[5]  = p1.y; a0r[6]  = p1.z; a0r[7]  = p1.w;
        a0r[8]  = p2.x; a0r[9]  = p2.y; a0r[10] = p2.z; a0r[11] = p2.w;
        a0r[12] = p3.x; a0r[13] = p3.y; a0r[14] = p3.z; a0r[15] = p3.w;
        a0r[16] = __fsub_rn(bxyz[3 * nbr],     qx);
        a0r[17] = __fsub_rn(bxyz[3 * nbr + 1], qy);
        a0r[18] = __fsub_rn(bxyz[3 * nbr + 2], qz);
    }

    float acc1[F1];
#pragma unroll
    for (int f = 0; f < F1; ++f) acc1[f] = 0.0f;

#pragma unroll 1
    for (int ch = 0; ch < F0 / 16; ++ch) {
        const float* __restrict__ W0c = w0 + ch * 16;
        float t[16];
#pragma unroll
        for (int j = 0; j < 16; ++j) t[j] = 0.0f;
#pragma unroll
        for (int c = 0; c < 19; ++c) {
            const float xc = a0r[c];
#pragma unroll
            for (int j = 0; j < 16; ++j)
                t[j] = fmaf(xc, W0c[c * F0 + j], t[j]);
        }
#pragma unroll
        for (int j = 0; j < 16; ++j) t[j] = fmaxf(t[j], 0.0f);

        const float* __restrict__ W1c = w1 + (size_t)ch * 16 * F1;
#pragma unroll
        for (int i = 0; i < 16; ++i) {
            const float xi = t[i];
#pragma unroll
            for (int f = 0; f < F1; ++f)
                acc1[f] = fmaf(xi, W1c[i * F1 + f], acc1[f]);
        }
    }
#pragma unroll
    for (int f = 0; f < F1; ++f) acc1[f] = fmaxf(acc1[f], 0.0f);

    float* outp = out1 + (size_t)qid * 320 + CH_OFF;
#pragma unroll 1
    for (int ch = 0; ch < F2 / 16; ++ch) {
        const float* __restrict__ Wc = w2 + ch * 16;
        float acc[16];
#pragma unroll
        for (int j = 0; j < 16; ++j) acc[j] = 0.0f;
#pragma unroll
        for (int c = 0; c < F1; ++c) {
            const float xc = acc1[c];
#pragma unroll
            for (int j = 0; j < 16; ++j)
                acc[j] = fmaf(xc, Wc[c * F2 + j], acc[j]);
        }
#pragma unroll
        for (int j = 0; j < 16; ++j) acc[j] = fmaxf(acc[j], 0.0f);
#pragma unroll
        for (int off = 1; off < K; off <<= 1) {
#pragma unroll
            for (int j = 0; j < 16; ++j)
                acc[j] = fmaxf(acc[j], __shfl_xor(acc[j], off));
        }
        if (k == 0) {
            float4* o = (float4*)(outp + ch * 16);
#pragma unroll
            for (int j = 0; j < 4; ++j)
                o[j] = make_float4(acc[4 * j + 0], acc[4 * j + 1],
                                   acc[4 * j + 2], acc[4 * j + 3]);
        }
    }
}

// ---------------------------------------------------------------------------
// Fused kernel: blocks 0-15 produce FPS; all 512 blocks then grid-stride over
// 7168 SA items (1024 sa0 + 2048 sa1 + 4096 sa2), spin-waiting per wave.
// Grid 512 == 2 blocks/CU LDS capacity -> all blocks resident, spins safe.
// ---------------------------------------------------------------------------
__global__ __launch_bounds__(256) void fused_kernel(
    const float* __restrict__ xyz,
    const float* __restrict__ points,
    const float* __restrict__ w00, const float* __restrict__ w01, const float* __restrict__ w02,
    const float* __restrict__ w10, const float* __restrict__ w11, const float* __restrict__ w12,
    const float* __restrict__ w20, const float* __restrict__ w21, const float* __restrict__ w22,
    float* __restrict__ out_nxyz,
    float* __restrict__ out_feat,
    float* __restrict__ out_idxf,
    int* __restrict__ progress)
{
    __shared__ __attribute__((aligned(16))) char smem[SMEM_BYTES];
    __shared__ float4 pr0[2][4];
    __shared__ float  pr1[2][4];

    if (blockIdx.x < BATCH)
        fps_role(xyz, out_nxyz, out_idxf, progress, smem, pr0, pr1);

    for (int v = blockIdx.x; v < 7168; v += GRID_BLOCKS) {
        if (v < 1024)
            sa_fp32_role<16, 32, 32, 64, 0>(v, xyz, points, out_nxyz,
                                            w00, w01, w02, out_feat,
                                            (float)(0.1 * 0.1), progress, smem);
        else if (v < 3072)
            sa_mfma_role<32, 64, 64, 128, 64>(v - 1024, xyz, points, out_nxyz,
                                              w10, w11, w12, out_feat,
                                              (float)(0.2 * 0.2), progress, smem);
        else
            sa_mfma_role<64, 64, 96, 128, 192>(v - 3072, xyz, points, out_nxyz,
                                               w20, w21, w22, out_feat,
                                               (float)(0.4 * 0.4), progress, smem);
    }
}

// ---------------------------------------------------------------------------
extern "C" void kernel_launch(void* const* d_in, const int* in_sizes, int n_in,
                              void* d_out, int out_size, void* d_ws, size_t ws_size,
                              hipStream_t stream)
{
    const float* xyz    = (const float*)d_in[0];
    const float* points = (const float*)d_in[1];
    const float* w00 = (const float*)d_in[2];
    const float* w01 = (const float*)d_in[3];
    const float* w02 = (const float*)d_in[4];
    const float* w10 = (const float*)d_in[5];
    const float* w11 = (const float*)d_in[6];
    const float* w12 = (const float*)d_in[7];
    const float* w20 = (const float*)d_in[8];
    const float* w21 = (const float*)d_in[9];
    const float* w22 = (const float*)d_in[10];

    float* out       = (float*)d_out;
    float* out_nxyz  = out;                       // 16*1024*3   = 49152
    float* out_feat  = out + 49152;               // 16*1024*320 = 5242880
    float* out_idxf  = out + 49152 + 5242880;     // 16*1024     = 16384

    int* progress = (int*)d_ws;                   // 16 ints
    hipMemsetAsync(progress, 0, BATCH * sizeof(int), stream);

    fused_kernel<<<GRID_BLOCKS, 256, 0, stream>>>(
        xyz, points,
        w00, w01, w02, w10, w11, w12, w20, w21, w22,
        out_nxyz, out_feat, out_idxf, progress);
}

// Round 14
// 937.199 us; speedup vs baseline: 1.8194x; 1.8194x over previous
//
#include <hip/hip_runtime.h>

#define NPTS 4096
#define NPT  1024
#define BATCH 16
#define GRID_BLOCKS 512
#define SMEM_BYTES 54272        // SA: act 53248 + slist 1024 ; FPS uses 49152
#define WAVE_ITEMS 28672        // 64 windows x 448 wave-items

typedef __attribute__((ext_vector_type(8))) short bf16x8;
typedef __attribute__((ext_vector_type(4))) float f32x4;

__device__ __forceinline__ unsigned short f2bf(float f) {
    unsigned u = __float_as_uint(f);
    u += 0x7fffu + ((u >> 16) & 1u);      // RNE; finite inputs only
    return (unsigned short)(u >> 16);
}

// ---------------------------------------------------------------------------
// DPP helper: packed u64 keymax carrying coords (FPS reduction).
// key = (float_bits(dist)<<32)|~idx; dist>=0 -> monotone bits; ~idx ties
// toward the smaller index (== jnp.argmax first-max).
// ---------------------------------------------------------------------------
template <int CTRL>
__device__ __forceinline__ void dpp_keymax_xyz(unsigned long long& key,
                                               float& x, float& y, float& z)
{
    const int klo = (int)(unsigned int)key;
    const int khi = (int)(unsigned int)(key >> 32);
    const int nlo = __builtin_amdgcn_update_dpp(0, klo, CTRL, 0xF, 0xF, false);
    const int nhi = __builtin_amdgcn_update_dpp(0, khi, CTRL, 0xF, 0xF, false);
    const int nx  = __builtin_amdgcn_update_dpp(0, __float_as_int(x), CTRL, 0xF, 0xF, false);
    const int ny  = __builtin_amdgcn_update_dpp(0, __float_as_int(y), CTRL, 0xF, 0xF, false);
    const int nz  = __builtin_amdgcn_update_dpp(0, __float_as_int(z), CTRL, 0xF, 0xF, false);
    const unsigned long long ok =
        ((unsigned long long)(unsigned int)nhi << 32) | (unsigned int)nlo;
    const bool gt = ok > key;
    key = gt ? ok : key;
    x = gt ? __int_as_float(nx) : x;
    y = gt ? __int_as_float(ny) : y;
    z = gt ? __int_as_float(nz) : z;
}

// RELAXED agent-scope poll: no cache invalidation per iteration (the r13
// ACQUIRE poll invalidated L1 every spin and wrecked co-resident compute).
__device__ __forceinline__ void wait_progress(int* progress, int b, int need)
{
    int guard = 0;
    while (__hip_atomic_load(&progress[b * 32], __ATOMIC_RELAXED,
                             __HIP_MEMORY_SCOPE_AGENT) < need) {
        if (++guard > (1 << 21)) break;   // fail loud, never hang
        __builtin_amdgcn_s_sleep(8);
    }
}

__device__ __forceinline__ float agent_loadf(const float* p)
{
    return __hip_atomic_load((float*)p, __ATOMIC_RELAXED,
                             __HIP_MEMORY_SCOPE_AGENT);
}
__device__ __forceinline__ void agent_storef(float* p, float v)
{
    __hip_atomic_store(p, v, __ATOMIC_RELAXED, __HIP_MEMORY_SCOPE_AGENT);
}

// ---------------------------------------------------------------------------
// FPS role (blocks 0..15): selection math bit-exact (r10-r12 form). Winner
// coords+index are in registers on every thread each step -> tid0 stores them
// straight to global via write-through (sc1) relaxed-agent stores (no LDS
// flush pass, no release fence). Publish progress[b] every 64 steps with
// s_waitcnt vmcnt(0) + relaxed agent store (prior stores are write-through,
// so this is a sufficient release for them). No wbl2, no L2 writeback storm.
// ---------------------------------------------------------------------------
__device__ void fps_role(const float* __restrict__ xyz,
                         float* __restrict__ out_nxyz,
                         float* __restrict__ out_idxf,
                         int* __restrict__ progress,
                         char* smem, float4 (*pr0)[4], float (*pr1)[4])
{
    float* sx = (float*)smem;
    float* sy = sx + NPTS;
    float* sz = sy + NPTS;

    const int tid  = threadIdx.x;
    const int b    = blockIdx.x;
    const int lane = tid & 63;
    const int wid  = tid >> 6;

    __builtin_amdgcn_s_setprio(1);   // keep the serial chain ahead of SA waves

    const float* bx = xyz + (size_t)b * NPTS * 3;
    for (int p = tid; p < NPTS; p += 256) {
        sx[p] = bx[3 * p];
        sy[p] = bx[3 * p + 1];
        sz[p] = bx[3 * p + 2];
    }
    __syncthreads();

    float rx[16], ry[16], rz[16], dist[16];
#pragma unroll
    for (int j = 0; j < 16; ++j) {
        const int p = tid + j * 256;
        rx[j] = sx[p]; ry[j] = sy[p]; rz[j] = sz[p];
        dist[j] = 1e10f;
    }
    float lx = sx[0], ly = sy[0], lz = sz[0];

    if (tid == 0) {
        float* o = out_nxyz + (size_t)b * NPT * 3;
        agent_storef(&o[0], lx);
        agent_storef(&o[1], ly);
        agent_storef(&o[2], lz);
        out_idxf[b * NPT] = 0.0f;
    }

    for (int step = 1; step < NPT; ++step) {
        float bv = -1.0f;
        int   bp = 0;
        float bxl = 0.0f, byl = 0.0f, bzl = 0.0f;
#pragma unroll
        for (int j = 0; j < 16; ++j) {
            const int p = tid + j * 256;
            const float dx = __fsub_rn(rx[j], lx);
            const float dy = __fsub_rn(ry[j], ly);
            const float dz = __fsub_rn(rz[j], lz);
            const float d  = __fadd_rn(__fadd_rn(__fmul_rn(dx, dx), __fmul_rn(dy, dy)),
                                       __fmul_rn(dz, dz));
            const float nd = fminf(dist[j], d);
            dist[j] = nd;
            const bool gt = nd > bv;
            bv  = gt ? nd    : bv;
            bp  = gt ? p     : bp;
            bxl = gt ? rx[j] : bxl;
            byl = gt ? ry[j] : byl;
            bzl = gt ? rz[j] : bzl;
        }
        unsigned long long key =
            ((unsigned long long)__float_as_uint(bv) << 32) |
            (unsigned int)(~bp);

        dpp_keymax_xyz<0x111>(key, bxl, byl, bzl);   // row_shr:1
        dpp_keymax_xyz<0x112>(key, bxl, byl, bzl);   // row_shr:2
        dpp_keymax_xyz<0x114>(key, bxl, byl, bzl);   // row_shr:4
        dpp_keymax_xyz<0x118>(key, bxl, byl, bzl);   // row_shr:8
        dpp_keymax_xyz<0x142>(key, bxl, byl, bzl);   // row_bcast15
        dpp_keymax_xyz<0x143>(key, bxl, byl, bzl);   // row_bcast31 -> lane63

        const int par = step & 1;
        if (lane == 63) {
            pr0[par][wid] = make_float4(
                __int_as_float((int)(unsigned int)key),
                __int_as_float((int)(unsigned int)(key >> 32)),
                bxl, byl);
            pr1[par][wid] = bzl;
        }
        __syncthreads();

        const float4 r   = pr0[par][lane & 3];
        const float  rzz = pr1[par][lane & 3];
        unsigned long long gkey =
            ((unsigned long long)(unsigned int)__float_as_int(r.y) << 32) |
            (unsigned int)__float_as_int(r.x);
        float gx = r.z, gy = r.w, gz = rzz;
        dpp_keymax_xyz<0xB1>(gkey, gx, gy, gz);   // quad_perm xor1
        dpp_keymax_xyz<0x4E>(gkey, gx, gy, gz);   // quad_perm xor2

        lx = gx; ly = gy; lz = gz;

        if (tid == 0) {
            const int ix = (int)(~(unsigned int)gkey);
            float* o = out_nxyz + (size_t)(b * NPT + step) * 3;
            agent_storef(&o[0], gx);
            agent_storef(&o[1], gy);
            agent_storef(&o[2], gz);
            out_idxf[b * NPT + step] = (float)ix;
            if ((step & 63) == 63) {
                asm volatile("s_waitcnt vmcnt(0)" ::: "memory");
                __hip_atomic_store(&progress[b * 32], step + 1,
                                   __ATOMIC_RELAXED, __HIP_MEMORY_SCOPE_AGENT);
            }
        }
        // single barrier per step (parity-double-buffered pr records)
    }
    __builtin_amdgcn_s_setprio(0);
}

// ---------------------------------------------------------------------------
// MFMA SA wave-item (K in {32,64}): r12's verified body at WAVE granularity.
// qid0 = first query of this wave. Per-wid LDS slices (act quarter + slist
// 64-entry slice) -> no barriers; waves drift freely across items.
// ---------------------------------------------------------------------------
template <int K, int F0, int F1, int F2, int CH_OFF>
__device__ void sa_mfma_wave(int qid0,
                             const float* __restrict__ xyz,
                             const float* __restrict__ points,
                             const float* __restrict__ newxyz,
                             const float* __restrict__ w0,
                             const float* __restrict__ w1,
                             const float* __restrict__ w2,
                             float* __restrict__ out1,
                             float r2, char* smem)
{
    constexpr int TPQ = K / 16;
    constexpr int QW  = 4 / TPQ;
    constexpr int KF1 = F0 / 32;
    constexpr int KF2 = F1 / 32;
    constexpr int NT0 = F0 / 16, NT1 = F1 / 16, NT2 = F2 / 16;
    constexpr int NH1 = NT1 / 2;
    constexpr int STRIDE = 104;
    constexpr unsigned long long KMASK =
        (K == 64) ? ~0ULL : ((1ULL << K) - 1ULL);

    const int lane = threadIdx.x & 63;
    const int wid  = threadIdx.x >> 6;
    unsigned short* __restrict__ A = (unsigned short*)smem + wid * 64 * STRIDE;
    int* __restrict__ slist = (int*)(smem + 4 * 64 * STRIDE * 2);

    const int k    = lane & (K - 1);
    const int qsub = lane / K;
    const int qid  = qid0 + qsub;
    const int b    = qid >> 10;

    const float qx = agent_loadf(&newxyz[(size_t)qid * 3 + 0]);
    const float qy = agent_loadf(&newxyz[(size_t)qid * 3 + 1]);
    const float qz = agent_loadf(&newxyz[(size_t)qid * 3 + 2]);
    const float* bxyz = xyz + (size_t)b * NPTS * 3;

    // ---- ball query (bit-exact fp32, first-K ascending) ----
    int cnt = 0;
    const int gbase = wid * 64 + qsub * K;
    for (int c0 = 0; c0 < NPTS; c0 += K) {
        bool hit = false;
        const int p = c0 + k;
        if (cnt < K) {
            const float dx = __fsub_rn(qx, bxyz[3 * p]);
            const float dy = __fsub_rn(qy, bxyz[3 * p + 1]);
            const float dz = __fsub_rn(qz, bxyz[3 * p + 2]);
            const float d2 = __fadd_rn(__fadd_rn(__fmul_rn(dx, dx), __fmul_rn(dy, dy)),
                                       __fmul_rn(dz, dz));
            hit = d2 < r2;
        }
        const unsigned long long bal = __ballot(hit);
        const unsigned long long gm  = (bal >> (qsub * K)) & KMASK;
        const int pre = __popcll(gm & ((1ULL << k) - 1ULL));
        const int pos = cnt + pre;
        if (hit && pos < K) slist[gbase + pos] = p;
        cnt = min(cnt + (int)__popcll(gm), K);
        if (__all(cnt >= K)) break;
    }
    const int nbr = slist[gbase + ((k < cnt) ? k : 0)];

    // ---- gather -> LDS bf16 row ----
    {
        unsigned short e[32];
        const float4* prow = (const float4*)(points + ((size_t)b * NPTS + nbr) * 16);
        const float4 p0 = prow[0], p1 = prow[1], p2 = prow[2], p3 = prow[3];
        e[0]  = f2bf(p0.x); e[1]  = f2bf(p0.y); e[2]  = f2bf(p0.z); e[3]  = f2bf(p0.w);
        e[4]  = f2bf(p1.x); e[5]  = f2bf(p1.y); e[6]  = f2bf(p1.z); e[7]  = f2bf(p1.w);
        e[8]  = f2bf(p2.x); e[9]  = f2bf(p2.y); e[10] = f2bf(p2.z); e[11] = f2bf(p2.w);
        e[12] = f2bf(p3.x); e[13] = f2bf(p3.y); e[14] = f2bf(p3.z); e[15] = f2bf(p3.w);
        e[16] = f2bf(__fsub_rn(bxyz[3 * nbr],     qx));
        e[17] = f2bf(__fsub_rn(bxyz[3 * nbr + 1], qy));
        e[18] = f2bf(__fsub_rn(bxyz[3 * nbr + 2], qz));
#pragma unroll
        for (int j = 19; j < 32; ++j) e[j] = 0;
        unsigned int* dst = (unsigned int*)&A[lane * STRIDE];
#pragma unroll
        for (int j = 0; j < 16; ++j)
            dst[j] = ((unsigned int)e[2 * j + 1] << 16) | e[2 * j];
    }

    const int lr = lane & 15;
    const int lg = lane >> 4;

    // ---- layer 1 ----
    bf16x8 a1[4];
#pragma unroll
    for (int m = 0; m < 4; ++m)
        a1[m] = *(const bf16x8*)&A[(m * 16 + lr) * STRIDE + lg * 8];

    bf16x8 b1[NT0];
#pragma unroll
    for (int n = 0; n < NT0; ++n) {
#pragma unroll
        for (int j = 0; j < 8; ++j) {
            const int kk = lg * 8 + j;
            const int kc = (kk < 19) ? kk : 18;
            const float v = w0[kc * F0 + n * 16 + lr];
            b1[n][j] = (kk < 19) ? (short)f2bf(v) : (short)0;
        }
    }
    f32x4 c1[4][NT0];
#pragma unroll
    for (int m = 0; m < 4; ++m)
#pragma unroll
        for (int n = 0; n < NT0; ++n) {
            f32x4 z = {0.0f, 0.0f, 0.0f, 0.0f};
            c1[m][n] = __builtin_amdgcn_mfma_f32_16x16x32_bf16(a1[m], b1[n], z, 0, 0, 0);
        }
#pragma unroll
    for (int m = 0; m < 4; ++m)
#pragma unroll
        for (int n = 0; n < NT0; ++n)
#pragma unroll
            for (int r = 0; r < 4; ++r)
                A[(m * 16 + lg * 4 + r) * STRIDE + n * 16 + lr] =
                    f2bf(fmaxf(c1[m][n][r], 0.0f));

    // ---- layer 2 (two n-halves) ----
    bf16x8 a2[4][KF1];
#pragma unroll
    for (int m = 0; m < 4; ++m)
#pragma unroll
        for (int kf = 0; kf < KF1; ++kf)
            a2[m][kf] = *(const bf16x8*)&A[(m * 16 + lr) * STRIDE + kf * 32 + lg * 8];

#pragma unroll
    for (int half = 0; half < 2; ++half) {
        bf16x8 b2[NH1][KF1];
#pragma unroll
        for (int n = 0; n < NH1; ++n)
#pragma unroll
            for (int kf = 0; kf < KF1; ++kf)
#pragma unroll
                for (int j = 0; j < 8; ++j) {
                    const int kk = kf * 32 + lg * 8 + j;
                    b2[n][kf][j] = (short)f2bf(w1[(size_t)kk * F1 + (half * NH1 + n) * 16 + lr]);
                }
        f32x4 c2[4][NH1];
#pragma unroll
        for (int m = 0; m < 4; ++m)
#pragma unroll
            for (int n = 0; n < NH1; ++n) {
                f32x4 z = {0.0f, 0.0f, 0.0f, 0.0f};
#pragma unroll
                for (int kf = 0; kf < KF1; ++kf)
                    z = __builtin_amdgcn_mfma_f32_16x16x32_bf16(a2[m][kf], b2[n][kf], z, 0, 0, 0);
                c2[m][n] = z;
            }
#pragma unroll
        for (int m = 0; m < 4; ++m)
#pragma unroll
            for (int n = 0; n < NH1; ++n)
#pragma unroll
                for (int r = 0; r < 4; ++r)
                    A[(m * 16 + lg * 4 + r) * STRIDE + (half * NH1 + n) * 16 + lr] =
                        f2bf(fmaxf(c2[m][n][r], 0.0f));
    }

    // ---- layer 3 + relu + pool + store ----
    bf16x8 a3[4][KF2];
#pragma unroll
    for (int m = 0; m < 4; ++m)
#pragma unroll
        for (int kf = 0; kf < KF2; ++kf)
            a3[m][kf] = *(const bf16x8*)&A[(m * 16 + lr) * STRIDE + kf * 32 + lg * 8];

#pragma unroll
    for (int n = 0; n < NT2; ++n) {
        bf16x8 b3[KF2];
#pragma unroll
        for (int kf = 0; kf < KF2; ++kf)
#pragma unroll
            for (int j = 0; j < 8; ++j) {
                const int kk = kf * 32 + lg * 8 + j;
                b3[kf][j] = (short)f2bf(w2[(size_t)kk * F2 + n * 16 + lr]);
            }
        float q0 = 0.0f, q1 = 0.0f;
#pragma unroll
        for (int m = 0; m < 4; ++m) {
            f32x4 c = {0.0f, 0.0f, 0.0f, 0.0f};
#pragma unroll
            for (int kf = 0; kf < KF2; ++kf)
                c = __builtin_amdgcn_mfma_f32_16x16x32_bf16(a3[m][kf], b3[kf], c, 0, 0, 0);
            float v = fmaxf(fmaxf(c[0], c[1]), fmaxf(c[2], c[3]));
            v = fmaxf(v, 0.0f);
            v = fmaxf(v, __shfl_xor(v, 16));
            v = fmaxf(v, __shfl_xor(v, 32));
            if (QW == 1) {
                q0 = fmaxf(q0, v);
            } else {
                if (m < 2) q0 = fmaxf(q0, v); else q1 = fmaxf(q1, v);
            }
        }
        if (lg < QW) {
            const float val = (QW == 2 && lg == 1) ? q1 : q0;
            out1[(size_t)(qid0 + lg) * 320 + CH_OFF + n * 16 + lr] = val;
        }
    }
}

// ---------------------------------------------------------------------------
// fp32 SA wave-item for scale 0 (K=16, 4 queries per wave) -- r7 fused stream.
// ---------------------------------------------------------------------------
template <int K, int F0, int F1, int F2, int CH_OFF>
__device__ void sa_fp32_wave(int qid0,
                             const float* __restrict__ xyz,
                             const float* __restrict__ points,
                             const float* __restrict__ newxyz,
                             const float* __restrict__ w0,
                             const float* __restrict__ w1,
                             const float* __restrict__ w2,
                             float* __restrict__ out1,
                             float r2, char* smem)
{
    constexpr unsigned long long KMASK = (1ULL << K) - 1ULL;

    int* __restrict__ slist = (int*)(smem + 4 * 64 * 104 * 2);

    const int lane = threadIdx.x & 63;
    const int wid  = threadIdx.x >> 6;
    const int k    = lane & (K - 1);
    const int qsub = lane / K;
    const int qid  = qid0 + qsub;
    const int b    = qid >> 10;

    const float qx = agent_loadf(&newxyz[(size_t)qid * 3 + 0]);
    const float qy = agent_loadf(&newxyz[(size_t)qid * 3 + 1]);
    const float qz = agent_loadf(&newxyz[(size_t)qid * 3 + 2]);
    const float* bxyz = xyz + (size_t)b * NPTS * 3;

    int cnt = 0;
    const int gbase = wid * 64 + qsub * K;
    for (int c0 = 0; c0 < NPTS; c0 += K) {
        bool hit = false;
        const int p = c0 + k;
        if (cnt < K) {
            const float dx = __fsub_rn(qx, bxyz[3 * p]);
            const float dy = __fsub_rn(qy, bxyz[3 * p + 1]);
            const float dz = __fsub_rn(qz, bxyz[3 * p + 2]);
            const float d2 = __fadd_rn(__fadd_rn(__fmul_rn(dx, dx), __fmul_rn(dy, dy)),
                                       __fmul_rn(dz, dz));
            hit = d2 < r2;
        }
        const unsigned long long bal = __ballot(hit);
        const unsigned long long gm  = (bal >> (qsub * K)) & KMASK;
        const int pre = __popcll(gm & ((1ULL << k) - 1ULL));
        const int pos = cnt + pre;
        if (hit && pos < K) slist[gbase + pos] = p;
        cnt = min(cnt + (int)__popcll(gm), K);
        if (__all(cnt >= K)) break;
    }
    const int nbr = slist[gbase + ((k < cnt) ? k : 0)];

    float a0r[19];
    {
        const float4* prow = (const float4*)(points + ((size_t)b * NPTS + nbr) * 16);
        const float4 p0 = prow[0], p1 = prow[1], p2 = prow[2], p3 = prow[3];
        a0r[0]  = p0.x; a0r[1]  = p0.y; a0r[2]  = p0.z; a0r[3]  = p0.w;
        a0r[4]  = p1.x; a0r[5]  = p1.y; a0r[6]  = p1.z; a0r[7]  = p1.w;
        a0r[8]  = p2.x; a0r[9]  = p2.y; a0r[10] = p2.z; a0r[11] = p2.w;
        a0r[12] = p3.x; a0r[13] = p3.y; a0r[14] = p3.z; a0r[15] = p3.w;
        a0r[16] = __fsub_rn(bxyz[3 * nbr],     qx);
        a0r[17] = __fsub_rn(bxyz[3 * nbr + 1], qy);
        a0r[18] = __fsub_rn(bxyz[3 * nbr + 2], qz);
    }

    float acc1[F1];
#pragma unroll
    for (int f = 0; f < F1; ++f) acc1[f] = 0.0f;

#pragma unroll 1
    for (int ch = 0; ch < F0 / 16; ++ch) {
        const float* __restrict__ W0c = w0 + ch * 16;
        float t[16];
#pragma unroll
        for (int j = 0; j < 16; ++j) t[j] = 0.0f;
#pragma unroll
        for (int c = 0; c < 19; ++c) {
            const float xc = a0r[c];
#pragma unroll
            for (int j = 0; j < 16; ++j)
                t[j] = fmaf(xc, W0c[c * F0 + j], t[j]);
        }
#pragma unroll
        for (int j = 0; j < 16; ++j) t[j] = fmaxf(t[j], 0.0f);

        const float* __restrict__ W1c = w1 + (size_t)ch * 16 * F1;
#pragma unroll
        for (int i = 0; i < 16; ++i) {
            const float xi = t[i];
#pragma unroll
            for (int f = 0; f < F1; ++f)
                acc1[f] = fmaf(xi, W1c[i * F1 + f], acc1[f]);
        }
    }
#pragma unroll
    for (int f = 0; f < F1; ++f) acc1[f] = fmaxf(acc1[f], 0.0f);

    float* outp = out1 + (size_t)qid * 320 + CH_OFF;
#pragma unroll 1
    for (int ch = 0; ch < F2 / 16; ++ch) {
        const float* __restrict__ Wc = w2 + ch * 16;
        float acc[16];
#pragma unroll
        for (int j = 0; j < 16; ++j) acc[j] = 0.0f;
#pragma unroll
        for (int c = 0; c < F1; ++c) {
            const float xc = acc1[c];
#pragma unroll
            for (int j = 0; j < 16; ++j)
                acc[j] = fmaf(xc, Wc[c * F2 + j], acc[j]);
        }
#pragma unroll
        for (int j = 0; j < 16; ++j) acc[j] = fmaxf(acc[j], 0.0f);
#pragma unroll
        for (int off = 1; off < K; off <<= 1) {
#pragma unroll
            for (int j = 0; j < 16; ++j)
                acc[j] = fmaxf(acc[j], __shfl_xor(acc[j], off));
        }
        if (k == 0) {
            float4* o = (float4*)(outp + ch * 16);
#pragma unroll
            for (int j = 0; j < 4; ++j)
                o[j] = make_float4(acc[4 * j + 0], acc[4 * j + 1],
                                   acc[4 * j + 2], acc[4 * j + 3]);
        }
    }
}

// ---------------------------------------------------------------------------
// Fused kernel. Blocks 0-15 produce FPS; ALL waves then pull wave-items from a
// global atomic counter (dynamic balancing: FPS blocks join late, take
// leftovers). Item order = 64 windows of 16 queries; within a window all 16
// batches' sa0 items, then sa1, then sa2 -> consumers track the producer.
// ---------------------------------------------------------------------------
__global__ __launch_bounds__(256) void fused_kernel(
    const float* __restrict__ xyz,
    const float* __restrict__ points,
    const float* __restrict__ w00, const float* __restrict__ w01, const float* __restrict__ w02,
    const float* __restrict__ w10, const float* __restrict__ w11, const float* __restrict__ w12,
    const float* __restrict__ w20, const float* __restrict__ w21, const float* __restrict__ w22,
    float* __restrict__ out_nxyz,
    float* __restrict__ out_feat,
    float* __restrict__ out_idxf,
    int* __restrict__ ws)
{
    __shared__ __attribute__((aligned(16))) char smem[SMEM_BYTES];
    __shared__ float4 pr0[2][4];
    __shared__ float  pr1[2][4];

    int* progress = ws;            // 16 counters, padded x32 ints (128 B apart)
    int* counter  = ws + 512;

    if (blockIdx.x < BATCH)
        fps_role(xyz, out_nxyz, out_idxf, progress, smem, pr0, pr1);

    const int lane = threadIdx.x & 63;
    while (true) {
        int u = 0;
        if (lane == 0) u = atomicAdd(counter, 1);
        u = __shfl(u, 0);
        if (u >= WAVE_ITEMS) break;

        const int w = u / 448;
        const int r = u % 448;
        const int b = r & 15;
        const int s = r >> 4;          // 0..27
        if (s < 4) {                   // sa0: 4 queries per wave
            const int q0l = w * 16 + s * 4;
            wait_progress(progress, b, q0l + 4);
            sa_fp32_wave<16, 32, 32, 64, 0>(b * 1024 + q0l, xyz, points,
                                            out_nxyz, w00, w01, w02, out_feat,
                                            (float)(0.1 * 0.1), smem);
        } else if (s < 12) {           // sa1: 2 queries per wave
            const int q0l = w * 16 + (s - 4) * 2;
            wait_progress(progress, b, q0l + 2);
            sa_mfma_wave<32, 64, 64, 128, 64>(b * 1024 + q0l, xyz, points,
                                              out_nxyz, w10, w11, w12, out_feat,
                                              (float)(0.2 * 0.2), smem);
        } else {                       // sa2: 1 query per wave
            const int q0l = w * 16 + (s - 12);
            wait_progress(progress, b, q0l + 1);
            sa_mfma_wave<64, 64, 96, 128, 192>(b * 1024 + q0l, xyz, points,
                                               out_nxyz, w20, w21, w22, out_feat,
                                               (float)(0.4 * 0.4), smem);
        }
    }
}

// ---------------------------------------------------------------------------
extern "C" void kernel_launch(void* const* d_in, const int* in_sizes, int n_in,
                              void* d_out, int out_size, void* d_ws, size_t ws_size,
                              hipStream_t stream)
{
    const float* xyz    = (const float*)d_in[0];
    const float* points = (const float*)d_in[1];
    const float* w00 = (const float*)d_in[2];
    const float* w01 = (const float*)d_in[3];
    const float* w02 = (const float*)d_in[4];
    const float* w10 = (const float*)d_in[5];
    const float* w11 = (const float*)d_in[6];
    const float* w12 = (const float*)d_in[7];
    const float* w20 = (const float*)d_in[8];
    const float* w21 = (const float*)d_in[9];
    const float* w22 = (const float*)d_in[10];

    float* out       = (float*)d_out;
    float* out_nxyz  = out;                       // 16*1024*3   = 49152
    float* out_feat  = out + 49152;               // 16*1024*320 = 5242880
    float* out_idxf  = out + 49152 + 5242880;     // 16*1024     = 16384

    int* ws = (int*)d_ws;                         // progress[512] + counter
    hipMemsetAsync(ws, 0, 4096, stream);

    fused_kernel<<<GRID_BLOCKS, 256, 0, stream>>>(
        xyz, points,
        w00, w01, w02, w10, w11, w12, w20, w21, w22,
        out_nxyz, out_feat, out_idxf, ws);
}

// Round 15
// 884.637 us; speedup vs baseline: 1.9275x; 1.0594x over previous
//
#include <hip/hip_runtime.h>

#define NPTS 4096
#define NPT  1024
#define BATCH 16
#define GRID_BLOCKS 512
#define SMEM_BYTES 54272        // SA: act 53248 + slist 1024 ; FPS uses 49152
#define WAVE_ITEMS 28672        // 64 windows x 448 wave-items

typedef __attribute__((ext_vector_type(8))) short bf16x8;
typedef __attribute__((ext_vector_type(4))) float f32x4;

__device__ __forceinline__ unsigned short f2bf(float f) {
    unsigned u = __float_as_uint(f);
    u += 0x7fffu + ((u >> 16) & 1u);      // RNE; finite inputs only
    return (unsigned short)(u >> 16);
}

__device__ __forceinline__ unsigned long long u64max(unsigned long long a,
                                                     unsigned long long b)
{
    return (a > b) ? a : b;   // v_cmp_lt_u64 + 2 cndmask, branchless
}

// ---------------------------------------------------------------------------
// DPP helper: key-only packed u64 keymax. key = (bits(dist)<<32)|~idx;
// dist>=0 -> monotone bits; ~idx ties toward smaller index (jnp.argmax).
// Identity 0 loses to every real key (lo = ~p != 0 for p <= 4095).
// ---------------------------------------------------------------------------
template <int CTRL>
__device__ __forceinline__ void dpp_keymax(unsigned long long& key)
{
    const int klo = (int)(unsigned int)key;
    const int khi = (int)(unsigned int)(key >> 32);
    const int nlo = __builtin_amdgcn_update_dpp(0, klo, CTRL, 0xF, 0xF, false);
    const int nhi = __builtin_amdgcn_update_dpp(0, khi, CTRL, 0xF, 0xF, false);
    const unsigned long long ok =
        ((unsigned long long)(unsigned int)nhi << 32) | (unsigned int)nlo;
    key = (ok > key) ? ok : key;
}

// RELAXED agent-scope poll: no per-iteration cache invalidation.
__device__ __forceinline__ void wait_progress(int* progress, int b, int need)
{
    int guard = 0;
    while (__hip_atomic_load(&progress[b * 32], __ATOMIC_RELAXED,
                             __HIP_MEMORY_SCOPE_AGENT) < need) {
        if (++guard > (1 << 21)) break;   // fail loud, never hang
        __builtin_amdgcn_s_sleep(8);
    }
}

__device__ __forceinline__ float agent_loadf(const float* p)
{
    return __hip_atomic_load((float*)p, __ATOMIC_RELAXED,
                             __HIP_MEMORY_SCOPE_AGENT);
}
__device__ __forceinline__ void agent_storef(float* p, float v)
{
    __hip_atomic_store(p, v, __ATOMIC_RELAXED, __HIP_MEMORY_SCOPE_AGENT);
}

// ---------------------------------------------------------------------------
// FPS role (blocks 0..15): selection math bit-exact (same key packing as
// r10-r14; max is associative so the 4-way accumulator tree changes nothing).
// SLIMMED: no coord carrying anywhere -- key-only local tree, key-only DPP
// wave reduce, key-only cross-wave quad_perm; winner coords via ONE broadcast
// LDS read of sx/sy/sz[ix] (same address across lanes, conflict-free).
// Priority 3: win CU-scheduler arbitration against co-resident SA waves.
// ---------------------------------------------------------------------------
__device__ void fps_role(const float* __restrict__ xyz,
                         float* __restrict__ out_nxyz,
                         float* __restrict__ out_idxf,
                         int* __restrict__ progress,
                         char* smem, unsigned long long (*pw)[4])
{
    float* sx = (float*)smem;
    float* sy = sx + NPTS;
    float* sz = sy + NPTS;

    const int tid  = threadIdx.x;
    const int b    = blockIdx.x;
    const int lane = tid & 63;
    const int wid  = tid >> 6;

    __builtin_amdgcn_s_setprio(3);

    const float* bx = xyz + (size_t)b * NPTS * 3;
    for (int p = tid; p < NPTS; p += 256) {
        sx[p] = bx[3 * p];
        sy[p] = bx[3 * p + 1];
        sz[p] = bx[3 * p + 2];
    }
    __syncthreads();

    float rx[16], ry[16], rz[16], dist[16];
#pragma unroll
    for (int j = 0; j < 16; ++j) {
        const int p = tid + j * 256;
        rx[j] = sx[p]; ry[j] = sy[p]; rz[j] = sz[p];
        dist[j] = 1e10f;
    }
    float lx = sx[0], ly = sy[0], lz = sz[0];

    if (tid == 0) {
        float* o = out_nxyz + (size_t)b * NPT * 3;
        agent_storef(&o[0], lx);
        agent_storef(&o[1], ly);
        agent_storef(&o[2], lz);
        out_idxf[b * NPT] = 0.0f;
    }

    for (int step = 1; step < NPT; ++step) {
        // ---- local 16-point update, 4-way ILP key-max accumulators ----
        unsigned long long b4[4] = {0ULL, 0ULL, 0ULL, 0ULL};
#pragma unroll
        for (int j = 0; j < 16; ++j) {
            const int p = tid + j * 256;
            const float dx = __fsub_rn(rx[j], lx);
            const float dy = __fsub_rn(ry[j], ly);
            const float dz = __fsub_rn(rz[j], lz);
            const float d  = __fadd_rn(__fadd_rn(__fmul_rn(dx, dx), __fmul_rn(dy, dy)),
                                       __fmul_rn(dz, dz));
            const float nd = fminf(dist[j], d);
            dist[j] = nd;
            const unsigned long long kj =
                ((unsigned long long)__float_as_uint(nd) << 32) |
                (unsigned int)(~p);
            b4[j & 3] = u64max(b4[j & 3], kj);
        }
        unsigned long long key =
            u64max(u64max(b4[0], b4[1]), u64max(b4[2], b4[3]));

        // ---- wave max-reduce via key-only DPP (result in lane 63) ----
        dpp_keymax<0x111>(key);   // row_shr:1
        dpp_keymax<0x112>(key);   // row_shr:2
        dpp_keymax<0x114>(key);   // row_shr:4
        dpp_keymax<0x118>(key);   // row_shr:8
        dpp_keymax<0x142>(key);   // row_bcast15
        dpp_keymax<0x143>(key);   // row_bcast31 -> lane63 = wave max

        const int par = step & 1;
        if (lane == 63) pw[par][wid] = key;
        __syncthreads();

        // ---- cross-wave: read record lane&3, quad_perm reduce 4 -> 1 ----
        unsigned long long gkey = pw[par][lane & 3];
        dpp_keymax<0xB1>(gkey);   // quad_perm xor1
        dpp_keymax<0x4E>(gkey);   // quad_perm xor2
        const int ix = (int)(~(unsigned int)gkey);

        // winner coords: one broadcast LDS read (same addr across lanes)
        lx = sx[ix]; ly = sy[ix]; lz = sz[ix];

        if (tid == 0) {
            float* o = out_nxyz + (size_t)(b * NPT + step) * 3;
            agent_storef(&o[0], lx);
            agent_storef(&o[1], ly);
            agent_storef(&o[2], lz);
            out_idxf[b * NPT + step] = (float)ix;
            if ((step & 63) == 63) {
                asm volatile("s_waitcnt vmcnt(0)" ::: "memory");
                __hip_atomic_store(&progress[b * 32], step + 1,
                                   __ATOMIC_RELAXED, __HIP_MEMORY_SCOPE_AGENT);
            }
        }
        // single barrier per step (parity-double-buffered pw records)
    }
    __builtin_amdgcn_s_setprio(0);
    __syncthreads();   // order final sx reads before SA items recycle smem
}

// ---------------------------------------------------------------------------
// MFMA SA wave-item (K in {32,64}): r12's verified body at WAVE granularity.
// Per-wid LDS slices (act quarter + slist slice) -> no barriers.
// ---------------------------------------------------------------------------
template <int K, int F0, int F1, int F2, int CH_OFF>
__device__ void sa_mfma_wave(int qid0,
                             const float* __restrict__ xyz,
                             const float* __restrict__ points,
                             const float* __restrict__ newxyz,
                             const float* __restrict__ w0,
                             const float* __restrict__ w1,
                             const float* __restrict__ w2,
                             float* __restrict__ out1,
                             float r2, char* smem)
{
    constexpr int TPQ = K / 16;
    constexpr int QW  = 4 / TPQ;
    constexpr int KF1 = F0 / 32;
    constexpr int KF2 = F1 / 32;
    constexpr int NT0 = F0 / 16, NT1 = F1 / 16, NT2 = F2 / 16;
    constexpr int NH1 = NT1 / 2;
    constexpr int STRIDE = 104;
    constexpr unsigned long long KMASK =
        (K == 64) ? ~0ULL : ((1ULL << K) - 1ULL);

    const int lane = threadIdx.x & 63;
    const int wid  = threadIdx.x >> 6;
    unsigned short* __restrict__ A = (unsigned short*)smem + wid * 64 * STRIDE;
    int* __restrict__ slist = (int*)(smem + 4 * 64 * STRIDE * 2);

    const int k    = lane & (K - 1);
    const int qsub = lane / K;
    const int qid  = qid0 + qsub;
    const int b    = qid >> 10;

    const float qx = agent_loadf(&newxyz[(size_t)qid * 3 + 0]);
    const float qy = agent_loadf(&newxyz[(size_t)qid * 3 + 1]);
    const float qz = agent_loadf(&newxyz[(size_t)qid * 3 + 2]);
    const float* bxyz = xyz + (size_t)b * NPTS * 3;

    // ---- ball query (bit-exact fp32, first-K ascending) ----
    int cnt = 0;
    const int gbase = wid * 64 + qsub * K;
    for (int c0 = 0; c0 < NPTS; c0 += K) {
        bool hit = false;
        const int p = c0 + k;
        if (cnt < K) {
            const float dx = __fsub_rn(qx, bxyz[3 * p]);
            const float dy = __fsub_rn(qy, bxyz[3 * p + 1]);
            const float dz = __fsub_rn(qz, bxyz[3 * p + 2]);
            const float d2 = __fadd_rn(__fadd_rn(__fmul_rn(dx, dx), __fmul_rn(dy, dy)),
                                       __fmul_rn(dz, dz));
            hit = d2 < r2;
        }
        const unsigned long long bal = __ballot(hit);
        const unsigned long long gm  = (bal >> (qsub * K)) & KMASK;
        const int pre = __popcll(gm & ((1ULL << k) - 1ULL));
        const int pos = cnt + pre;
        if (hit && pos < K) slist[gbase + pos] = p;
        cnt = min(cnt + (int)__popcll(gm), K);
        if (__all(cnt >= K)) break;
    }
    const int nbr = slist[gbase + ((k < cnt) ? k : 0)];

    // ---- gather -> LDS bf16 row ----
    {
        unsigned short e[32];
        const float4* prow = (const float4*)(points + ((size_t)b * NPTS + nbr) * 16);
        const float4 p0 = prow[0], p1 = prow[1], p2 = prow[2], p3 = prow[3];
        e[0]  = f2bf(p0.x); e[1]  = f2bf(p0.y); e[2]  = f2bf(p0.z); e[3]  = f2bf(p0.w);
        e[4]  = f2bf(p1.x); e[5]  = f2bf(p1.y); e[6]  = f2bf(p1.z); e[7]  = f2bf(p1.w);
        e[8]  = f2bf(p2.x); e[9]  = f2bf(p2.y); e[10] = f2bf(p2.z); e[11] = f2bf(p2.w);
        e[12] = f2bf(p3.x); e[13] = f2bf(p3.y); e[14] = f2bf(p3.z); e[15] = f2bf(p3.w);
        e[16] = f2bf(__fsub_rn(bxyz[3 * nbr],     qx));
        e[17] = f2bf(__fsub_rn(bxyz[3 * nbr + 1], qy));
        e[18] = f2bf(__fsub_rn(bxyz[3 * nbr + 2], qz));
#pragma unroll
        for (int j = 19; j < 32; ++j) e[j] = 0;
        unsigned int* dst = (unsigned int*)&A[lane * STRIDE];
#pragma unroll
        for (int j = 0; j < 16; ++j)
            dst[j] = ((unsigned int)e[2 * j + 1] << 16) | e[2 * j];
    }

    const int lr = lane & 15;
    const int lg = lane >> 4;

    // ---- layer 1 ----
    bf16x8 a1[4];
#pragma unroll
    for (int m = 0; m < 4; ++m)
        a1[m] = *(const bf16x8*)&A[(m * 16 + lr) * STRIDE + lg * 8];

    bf16x8 b1[NT0];
#pragma unroll
    for (int n = 0; n < NT0; ++n) {
#pragma unroll
        for (int j = 0; j < 8; ++j) {
            const int kk = lg * 8 + j;
            const int kc = (kk < 19) ? kk : 18;
            const float v = w0[kc * F0 + n * 16 + lr];
            b1[n][j] = (kk < 19) ? (short)f2bf(v) : (short)0;
        }
    }
    f32x4 c1[4][NT0];
#pragma unroll
    for (int m = 0; m < 4; ++m)
#pragma unroll
        for (int n = 0; n < NT0; ++n) {
            f32x4 z = {0.0f, 0.0f, 0.0f, 0.0f};
            c1[m][n] = __builtin_amdgcn_mfma_f32_16x16x32_bf16(a1[m], b1[n], z, 0, 0, 0);
        }
#pragma unroll
    for (int m = 0; m < 4; ++m)
#pragma unroll
        for (int n = 0; n < NT0; ++n)
#pragma unroll
            for (int r = 0; r < 4; ++r)
                A[(m * 16 + lg * 4 + r) * STRIDE + n * 16 + lr] =
                    f2bf(fmaxf(c1[m][n][r], 0.0f));

    // ---- layer 2 (two n-halves) ----
    bf16x8 a2[4][KF1];
#pragma unroll
    for (int m = 0; m < 4; ++m)
#pragma unroll
        for (int kf = 0; kf < KF1; ++kf)
            a2[m][kf] = *(const bf16x8*)&A[(m * 16 + lr) * STRIDE + kf * 32 + lg * 8];

#pragma unroll
    for (int half = 0; half < 2; ++half) {
        bf16x8 b2[NH1][KF1];
#pragma unroll
        for (int n = 0; n < NH1; ++n)
#pragma unroll
            for (int kf = 0; kf < KF1; ++kf)
#pragma unroll
                for (int j = 0; j < 8; ++j) {
                    const int kk = kf * 32 + lg * 8 + j;
                    b2[n][kf][j] = (short)f2bf(w1[(size_t)kk * F1 + (half * NH1 + n) * 16 + lr]);
                }
        f32x4 c2[4][NH1];
#pragma unroll
        for (int m = 0; m < 4; ++m)
#pragma unroll
            for (int n = 0; n < NH1; ++n) {
                f32x4 z = {0.0f, 0.0f, 0.0f, 0.0f};
#pragma unroll
                for (int kf = 0; kf < KF1; ++kf)
                    z = __builtin_amdgcn_mfma_f32_16x16x32_bf16(a2[m][kf], b2[n][kf], z, 0, 0, 0);
                c2[m][n] = z;
            }
#pragma unroll
        for (int m = 0; m < 4; ++m)
#pragma unroll
            for (int n = 0; n < NH1; ++n)
#pragma unroll
                for (int r = 0; r < 4; ++r)
                    A[(m * 16 + lg * 4 + r) * STRIDE + (half * NH1 + n) * 16 + lr] =
                        f2bf(fmaxf(c2[m][n][r], 0.0f));
    }

    // ---- layer 3 + relu + pool + store ----
    bf16x8 a3[4][KF2];
#pragma unroll
    for (int m = 0; m < 4; ++m)
#pragma unroll
        for (int kf = 0; kf < KF2; ++kf)
            a3[m][kf] = *(const bf16x8*)&A[(m * 16 + lr) * STRIDE + kf * 32 + lg * 8];

#pragma unroll
    for (int n = 0; n < NT2; ++n) {
        bf16x8 b3[KF2];
#pragma unroll
        for (int kf = 0; kf < KF2; ++kf)
#pragma unroll
            for (int j = 0; j < 8; ++j) {
                const int kk = kf * 32 + lg * 8 + j;
                b3[kf][j] = (short)f2bf(w2[(size_t)kk * F2 + n * 16 + lr]);
            }
        float q0 = 0.0f, q1 = 0.0f;
#pragma unroll
        for (int m = 0; m < 4; ++m) {
            f32x4 c = {0.0f, 0.0f, 0.0f, 0.0f};
#pragma unroll
            for (int kf = 0; kf < KF2; ++kf)
                c = __builtin_amdgcn_mfma_f32_16x16x32_bf16(a3[m][kf], b3[kf], c, 0, 0, 0);
            float v = fmaxf(fmaxf(c[0], c[1]), fmaxf(c[2], c[3]));
            v = fmaxf(v, 0.0f);
            v = fmaxf(v, __shfl_xor(v, 16));
            v = fmaxf(v, __shfl_xor(v, 32));
            if (QW == 1) {
                q0 = fmaxf(q0, v);
            } else {
                if (m < 2) q0 = fmaxf(q0, v); else q1 = fmaxf(q1, v);
            }
        }
        if (lg < QW) {
            const float val = (QW == 2 && lg == 1) ? q1 : q0;
            out1[(size_t)(qid0 + lg) * 320 + CH_OFF + n * 16 + lr] = val;
        }
    }
}

// ---------------------------------------------------------------------------
// fp32 SA wave-item for scale 0 (K=16, 4 queries per wave).
// ---------------------------------------------------------------------------
template <int K, int F0, int F1, int F2, int CH_OFF>
__device__ void sa_fp32_wave(int qid0,
                             const float* __restrict__ xyz,
                             const float* __restrict__ points,
                             const float* __restrict__ newxyz,
                             const float* __restrict__ w0,
                             const float* __restrict__ w1,
                             const float* __restrict__ w2,
                             float* __restrict__ out1,
                             float r2, char* smem)
{
    constexpr unsigned long long KMASK = (1ULL << K) - 1ULL;

    int* __restrict__ slist = (int*)(smem + 4 * 64 * 104 * 2);

    const int lane = threadIdx.x & 63;
    const int wid  = threadIdx.x >> 6;
    const int k    = lane & (K - 1);
    const int qsub = lane / K;
    const int qid  = qid0 + qsub;
    const int b    = qid >> 10;

    const float qx = agent_loadf(&newxyz[(size_t)qid * 3 + 0]);
    const float qy = agent_loadf(&newxyz[(size_t)qid * 3 + 1]);
    const float qz = agent_loadf(&newxyz[(size_t)qid * 3 + 2]);
    const float* bxyz = xyz + (size_t)b * NPTS * 3;

    int cnt = 0;
    const int gbase = wid * 64 + qsub * K;
    for (int c0 = 0; c0 < NPTS; c0 += K) {
        bool hit = false;
        const int p = c0 + k;
        if (cnt < K) {
            const float dx = __fsub_rn(qx, bxyz[3 * p]);
            const float dy = __fsub_rn(qy, bxyz[3 * p + 1]);
            const float dz = __fsub_rn(qz, bxyz[3 * p + 2]);
            const float d2 = __fadd_rn(__fadd_rn(__fmul_rn(dx, dx), __fmul_rn(dy, dy)),
                                       __fmul_rn(dz, dz));
            hit = d2 < r2;
        }
        const unsigned long long bal = __ballot(hit);
        const unsigned long long gm  = (bal >> (qsub * K)) & KMASK;
        const int pre = __popcll(gm & ((1ULL << k) - 1ULL));
        const int pos = cnt + pre;
        if (hit && pos < K) slist[gbase + pos] = p;
        cnt = min(cnt + (int)__popcll(gm), K);
        if (__all(cnt >= K)) break;
    }
    const int nbr = slist[gbase + ((k < cnt) ? k : 0)];

    float a0r[19];
    {
        const float4* prow = (const float4*)(points + ((size_t)b * NPTS + nbr) * 16);
        const float4 p0 = prow[0], p1 = prow[1], p2 = prow[2], p3 = prow[3];
        a0r[0]  = p0.x; a0r[1]  = p0.y; a0r[2]  = p0.z; a0r[3]  = p0.w;
        a0r[4]  = p1.x; a0r[5]  = p1.y; a0r[6]  = p1.z; a0r[7]  = p1.w;
        a0r[8]  = p2.x; a0r[9]  = p2.y; a0r[10] = p2.z; a0r[11] = p2.w;
        a0r[12] = p3.x; a0r[13] = p3.y; a0r[14] = p3.z; a0r[15] = p3.w;
        a0r[16] = __fsub_rn(bxyz[3 * nbr],     qx);
        a0r[17] = __fsub_rn(bxyz[3 * nbr + 1], qy);
        a0r[18] = __fsub_rn(bxyz[3 * nbr + 2], qz);
    }

    float acc1[F1];
#pragma unroll
    for (int f = 0; f < F1; ++f) acc1[f] = 0.0f;

#pragma unroll 1
    for (int ch = 0; ch < F0 / 16; ++ch) {
        const float* __restrict__ W0c = w0 + ch * 16;
        float t[16];
#pragma unroll
        for (int j = 0; j < 16; ++j) t[j] = 0.0f;
#pragma unroll
        for (int c = 0; c < 19; ++c) {
            const float xc = a0r[c];
#pragma unroll
            for (int j = 0; j < 16; ++j)
                t[j] = fmaf(xc, W0c[c * F0 + j], t[j]);
        }
#pragma unroll
        for (int j = 0; j < 16; ++j) t[j] = fmaxf(t[j], 0.0f);

        const float* __restrict__ W1c = w1 + (size_t)ch * 16 * F1;
#pragma unroll
        for (int i = 0; i < 16; ++i) {
            const float xi = t[i];
#pragma unroll
            for (int f = 0; f < F1; ++f)
                acc1[f] = fmaf(xi, W1c[i * F1 + f], acc1[f]);
        }
    }
#pragma unroll
    for (int f = 0; f < F1; ++f) acc1[f] = fmaxf(acc1[f], 0.0f);

    float* outp = out1 + (size_t)qid * 320 + CH_OFF;
#pragma unroll 1
    for (int ch = 0; ch < F2 / 16; ++ch) {
        const float* __restrict__ Wc = w2 + ch * 16;
        float acc[16];
#pragma unroll
        for (int j = 0; j < 16; ++j) acc[j] = 0.0f;
#pragma unroll
        for (int c = 0; c < F1; ++c) {
            const float xc = acc1[c];
#pragma unroll
            for (int j = 0; j < 16; ++j)
                acc[j] = fmaf(xc, Wc[c * F2 + j], acc[j]);
        }
#pragma unroll
        for (int j = 0; j < 16; ++j) acc[j] = fmaxf(acc[j], 0.0f);
#pragma unroll
        for (int off = 1; off < K; off <<= 1) {
#pragma unroll
            for (int j = 0; j < 16; ++j)
                acc[j] = fmaxf(acc[j], __shfl_xor(acc[j], off));
        }
        if (k == 0) {
            float4* o = (float4*)(outp + ch * 16);
#pragma unroll
            for (int j = 0; j < 4; ++j)
                o[j] = make_float4(acc[4 * j + 0], acc[4 * j + 1],
                                   acc[4 * j + 2], acc[4 * j + 3]);
        }
    }
}

// ---------------------------------------------------------------------------
// Fused kernel. Blocks 0-15 produce FPS; ALL waves then pull wave-items from a
// global atomic counter. Item order = 64 windows of 16 queries; within a
// window all 16 batches' sa0 items, then sa1, then sa2.
// ---------------------------------------------------------------------------
__global__ __launch_bounds__(256) void fused_kernel(
    const float* __restrict__ xyz,
    const float* __restrict__ points,
    const float* __restrict__ w00, const float* __restrict__ w01, const float* __restrict__ w02,
    const float* __restrict__ w10, const float* __restrict__ w11, const float* __restrict__ w12,
    const float* __restrict__ w20, const float* __restrict__ w21, const float* __restrict__ w22,
    float* __restrict__ out_nxyz,
    float* __restrict__ out_feat,
    float* __restrict__ out_idxf,
    int* __restrict__ ws)
{
    __shared__ __attribute__((aligned(16))) char smem[SMEM_BYTES];
    __shared__ unsigned long long pw[2][4];

    int* progress = ws;            // 16 counters, padded x32 ints (128 B apart)
    int* counter  = ws + 512;

    if (blockIdx.x < BATCH)
        fps_role(xyz, out_nxyz, out_idxf, progress, smem, pw);

    const int lane = threadIdx.x & 63;
    while (true) {
        int u = 0;
        if (lane == 0) u = atomicAdd(counter, 1);
        u = __shfl(u, 0);
        if (u >= WAVE_ITEMS) break;

        const int w = u / 448;
        const int r = u % 448;
        const int b = r & 15;
        const int s = r >> 4;          // 0..27
        if (s < 4) {                   // sa0: 4 queries per wave
            const int q0l = w * 16 + s * 4;
            wait_progress(progress, b, q0l + 4);
            sa_fp32_wave<16, 32, 32, 64, 0>(b * 1024 + q0l, xyz, points,
                                            out_nxyz, w00, w01, w02, out_feat,
                                            (float)(0.1 * 0.1), smem);
        } else if (s < 12) {           // sa1: 2 queries per wave
            const int q0l = w * 16 + (s - 4) * 2;
            wait_progress(progress, b, q0l + 2);
            sa_mfma_wave<32, 64, 64, 128, 64>(b * 1024 + q0l, xyz, points,
                                              out_nxyz, w10, w11, w12, out_feat,
                                              (float)(0.2 * 0.2), smem);
        } else {                       // sa2: 1 query per wave
            const int q0l = w * 16 + (s - 12);
            wait_progress(progress, b, q0l + 1);
            sa_mfma_wave<64, 64, 96, 128, 192>(b * 1024 + q0l, xyz, points,
                                               out_nxyz, w20, w21, w22, out_feat,
                                               (float)(0.4 * 0.4), smem);
        }
    }
}

// ---------------------------------------------------------------------------
extern "C" void kernel_launch(void* const* d_in, const int* in_sizes, int n_in,
                              void* d_out, int out_size, void* d_ws, size_t ws_size,
                              hipStream_t stream)
{
    const float* xyz    = (const float*)d_in[0];
    const float* points = (const float*)d_in[1];
    const float* w00 = (const float*)d_in[2];
    const float* w01 = (const float*)d_in[3];
    const float* w02 = (const float*)d_in[4];
    const float* w10 = (const float*)d_in[5];
    const float* w11 = (const float*)d_in[6];
    const float* w12 = (const float*)d_in[7];
    const float* w20 = (const float*)d_in[8];
    const float* w21 = (const float*)d_in[9];
    const float* w22 = (const float*)d_in[10];

    float* out       = (float*)d_out;
    float* out_nxyz  = out;                       // 16*1024*3   = 49152
    float* out_feat  = out + 49152;               // 16*1024*320 = 5242880
    float* out_idxf  = out + 49152 + 5242880;     // 16*1024     = 16384

    int* ws = (int*)d_ws;                         // progress[512] + counter
    hipMemsetAsync(ws, 0, 4096, stream);

    fused_kernel<<<GRID_BLOCKS, 256, 0, stream>>>(
        xyz, points,
        w00, w01, w02, w10, w11, w12, w20, w21, w22,
        out_nxyz, out_feat, out_idxf, ws);
}